// Round 6
// baseline (482.321 us; speedup 1.0000x reference)
//
#include <hip/hip_runtime.h>
#include <stdint.h>

// Problem constants (from reference): B=4, S=4096, D=2, 3 RK2 steps.
#define BATCH   4
#define SEQ     4096
#define NROWS   (BATCH * SEQ)       // 16384
#define MAXC    96                  // cols/row: mean 41, sd 6.4; 96 = +8.6 sigma
#define DTS     0.1f
#define HALF_DT 0.05f
#define EPS     1e-8f

// ---------------------------------------------------------------------------
// Kernel 1: mask -> fixed-stride CSR (uint16 col indices + count per row).
// Wave-per-row; 16 hoisted float4 loads (16 KB/wave in flight), popcount,
// wave prefix-scan, scattered uint16 index writes. Benched equal to all
// other compress variants (~55 us) — the mask read is the floor.
// ---------------------------------------------------------------------------
__global__ __launch_bounds__(256)
void compress_csr(const float* __restrict__ mask,
                  unsigned short* __restrict__ csr,
                  int* __restrict__ cnts) {
    const int row  = (blockIdx.x * blockDim.x + threadIdx.x) >> 6;
    const int lane = threadIdx.x & 63;
    const float4* src = reinterpret_cast<const float4*>(mask + (size_t)row * SEQ);

    float4 d[16];
#pragma unroll
    for (int c = 0; c < 16; ++c) d[c] = src[c * 64 + lane];

    int n = 0;
#pragma unroll
    for (int c = 0; c < 16; ++c)
        n += (d[c].x != 0.f) + (d[c].y != 0.f) + (d[c].z != 0.f) + (d[c].w != 0.f);

    int inc = n;
#pragma unroll
    for (int dd = 1; dd < 64; dd <<= 1) {
        int t = __shfl_up(inc, dd, 64);
        if (lane >= dd) inc += t;
    }
    int excl  = inc - n;
    int total = __shfl(inc, 63, 64);
    if (lane == 0) cnts[row] = (total < MAXC) ? total : MAXC;

    unsigned short* dst = csr + (size_t)row * MAXC;   // 192 B stride, 16B-aligned
    int k = excl;
    const int cb = lane << 2;
#pragma unroll
    for (int c = 0; c < 16; ++c) {
        const int col = c * 256 + cb;
        if (d[c].x != 0.f) { if (k < MAXC) dst[k] = (unsigned short)(col + 0); ++k; }
        if (d[c].y != 0.f) { if (k < MAXC) dst[k] = (unsigned short)(col + 1); ++k; }
        if (d[c].z != 0.f) { if (k < MAXC) dst[k] = (unsigned short)(col + 2); ++k; }
        if (d[c].w != 0.f) { if (k < MAXC) dst[k] = (unsigned short)(col + 3); ++k; }
    }
}

// 8 indices per uint4 chunk; accumulate LDS gathers, predicated on i<cnt.
__device__ __forceinline__ void gather8(const float2* __restrict__ lds,
                                        uint4 q, int base, int cnt,
                                        float& sx, float& sy) {
    unsigned id[8] = { q.x & 0xffffu, q.x >> 16, q.y & 0xffffu, q.y >> 16,
                       q.z & 0xffffu, q.z >> 16, q.w & 0xffffu, q.w >> 16 };
#pragma unroll
    for (int e = 0; e < 8; ++e) {
        if (base + e < cnt) {
            float2 v = lds[id[e]];
            sx += v.x; sy += v.y;
        }
    }
}

__device__ __forceinline__ float2 row_sum(const unsigned short* __restrict__ cs,
                                          int cnt, const float2* __restrict__ lds) {
    const uint4* cv = reinterpret_cast<const uint4*>(cs);
    float sx = 0.f, sy = 0.f;
    for (int c = 0; c * 8 < cnt; ++c)
        gather8(lds, cv[c], c * 8, cnt, sx, sy);
    return make_float2(sx, sy);
}

// ---------------------------------------------------------------------------
// Kernel 2: full 3-step RK2 integration. One 1024-thread workgroup per batch
// (grid=4). p and star live in LDS (32 KB each); k1/r in registers (each
// thread owns rows t, t+1024, t+2048, t+3072). __syncthreads() (~100 cyc)
// replaces the 6 kernel boundaries / 200-us device-scope grid syncs.
// ---------------------------------------------------------------------------
__global__ __launch_bounds__(1024, 1)
void integrate(const unsigned short* __restrict__ csr,
               const int* __restrict__ cnts,
               const float2* __restrict__ psi,
               float2* __restrict__ out) {
    __shared__ float2 pl[SEQ];    // current state
    __shared__ float2 sl[SEQ];    // psi_star
    const int b = blockIdx.x;
    const int t = threadIdx.x;
    const int rbase = b << 12;

    // Load batch state into LDS (coalesced) + per-row counts.
    int cnt[4];
    const float2* pb = psi + ((size_t)b << 12);
#pragma unroll
    for (int j = 0; j < 4; ++j) {
        const int row = j * 1024 + t;
        pl[row] = pb[row];
        cnt[j]  = cnts[rbase + row];
    }
    __syncthreads();

    float2 k1r[4];
    float  rr[4];

    for (int s = 0; s < 3; ++s) {
        // Phase A: k1 = M@p - p; star = renorm(p + DT*k1, r)
#pragma unroll
        for (int j = 0; j < 4; ++j) {
            const int row = j * 1024 + t;
            const unsigned short* cs = csr + (size_t)(rbase + row) * MAXC;
            float2 sum = row_sum(cs, cnt[j], pl);
            float2 p  = pl[row];
            float r   = sqrtf(p.x * p.x + p.y * p.y);
            float k1x = sum.x - p.x, k1y = sum.y - p.y;
            float tx  = p.x + DTS * k1x, ty = p.y + DTS * k1y;
            float sc  = r / (sqrtf(tx * tx + ty * ty) + EPS);
            k1r[j] = make_float2(k1x, k1y);
            rr[j]  = r;
            sl[row] = make_float2(tx * sc, ty * sc);
        }
        __syncthreads();

        // Phase B: k2 = M@star - star; p_new = renorm(p + DT/2*(k1+k2), r)
#pragma unroll
        for (int j = 0; j < 4; ++j) {
            const int row = j * 1024 + t;
            const unsigned short* cs = csr + (size_t)(rbase + row) * MAXC;
            float2 sum = row_sum(cs, cnt[j], sl);
            float2 st = sl[row];
            float2 p  = pl[row];
            float k2x = sum.x - st.x, k2y = sum.y - st.y;
            float nx  = p.x + HALF_DT * (k1r[j].x + k2x);
            float ny  = p.y + HALF_DT * (k1r[j].y + k2y);
            float sc  = rr[j] / (sqrtf(nx * nx + ny * ny) + EPS);
            float2 pn = make_float2(nx * sc, ny * sc);
            if (s == 2) out[rbase + row] = pn;   // final: straight to d_out
            else        pl[row] = pn;            // own-row write, no race
        }
        __syncthreads();
    }
}

extern "C" void kernel_launch(void* const* d_in, const int* in_sizes, int n_in,
                              void* d_out, int out_size, void* d_ws, size_t ws_size,
                              hipStream_t stream) {
    const float* psi  = (const float*)d_in[0];   // [4,4096,2] fp32
    const float* mask = (const float*)d_in[1];   // [4,4096,4096] fp32 (0/1)
    float2* out2 = (float2*)d_out;               // [4,4096,2] fp32

    // Workspace: cnts 64 KB | csr 3 MB (16384 rows x 96 x u16)
    char* ws = (char*)d_ws;
    int* cnts = (int*)ws;
    unsigned short* csr = (unsigned short*)(cnts + NROWS);

    const float2* psi2 = (const float2*)psi;

    compress_csr<<<NROWS / 4, 256, 0, stream>>>(mask, csr, cnts);
    integrate<<<BATCH, 1024, 0, stream>>>(csr, cnts, psi2, out2);
}

// Round 7
// 400.568 us; speedup vs baseline: 1.2041x; 1.2041x over previous
//
#include <hip/hip_runtime.h>
#include <stdint.h>

// Problem constants (from reference): B=4, S=4096, D=2, 3 RK2 steps.
#define BATCH   4
#define SEQ     4096
#define NROWS   (BATCH * SEQ)           // 16384
#define DTS     0.1f
#define HALF_DT 0.05f
#define EPS     1e-8f

// Byte-mask: byte P holds flags for cols/floats [8P, 8P+8) of the flat mask.
// Row r occupies bytes [512r, 512r+512). Total 8 MB.
#define TOT_BYTES (NROWS * (SEQ / 8))   // 8,388,608

// Compress grid: thread-linear, zero cross-lane ops.
#define CB_BLOCKS 4096
#define CB_THR    256
#define CB_NT     (CB_BLOCKS * CB_THR)  // 1,048,576 threads
#define CB_ITERS  (TOT_BYTES / CB_NT)   // 8

// ---------------------------------------------------------------------------
// Kernel 1: mask -> byte-mask. Per iteration each thread loads 2 consecutive
// float4 (32 B), packs 8 compare bits into one byte, stores 1 byte (64 B/wave
// coalesced). No ballots / prefix scans / divergence anywhere: nothing blocks
// the compiler from keeping many loads in flight. Pure streaming read.
// ---------------------------------------------------------------------------
__global__ __launch_bounds__(CB_THR)
void compress_bytes(const float* __restrict__ mask,
                    unsigned char* __restrict__ bytes) {
    const int t = blockIdx.x * CB_THR + threadIdx.x;
    const float4* m4 = reinterpret_cast<const float4*>(mask);
#pragma unroll
    for (int k = 0; k < CB_ITERS; ++k) {
        const size_t P = (size_t)k * CB_NT + t;
        float4 a = m4[2 * P];
        float4 b = m4[2 * P + 1];
        unsigned v = (unsigned)(a.x != 0.f)
                   | ((unsigned)(a.y != 0.f) << 1)
                   | ((unsigned)(a.z != 0.f) << 2)
                   | ((unsigned)(a.w != 0.f) << 3)
                   | ((unsigned)(b.x != 0.f) << 4)
                   | ((unsigned)(b.y != 0.f) << 5)
                   | ((unsigned)(b.z != 0.f) << 6)
                   | ((unsigned)(b.w != 0.f) << 7);
        bytes[P] = (unsigned char)v;
    }
}

// ---------------------------------------------------------------------------
// Force + RK2-stage update. Wave-per-row: lane l loads the aligned u64 at
// row_bytes + 8l (coalesced 512 B/row), covering cols [64l, 64l+64); bit j
// (little-endian) <-> col 64l + j. ctz loop gathers float2 state from the
// 32 KB L1-resident batch window; 64-lane xor butterfly; lane 0 epilogue.
// PHASE 0: k1 = M@p - p; star = renorm(p + DT*k1, r);  writes k1,star,r.
// PHASE 1: k2 = M@star - star; p_new = renorm(p + DT/2*(k1+k2), r) -> outbuf.
// ---------------------------------------------------------------------------
template <int PHASE>
__global__ __launch_bounds__(256)
void force_step(const unsigned char* __restrict__ bytes,
                const float2* __restrict__ pIn,     // current state
                const float2* __restrict__ gsrc,    // gather source (p or star)
                float2* __restrict__ k1buf,
                float2* __restrict__ starbuf,
                float*  __restrict__ rbuf,
                float2* __restrict__ outbuf) {
    const int row  = (blockIdx.x * blockDim.x + threadIdx.x) >> 6;
    const int lane = threadIdx.x & 63;
    const int bidx = row >> 12;
    const float2* gb = gsrc + ((size_t)bidx << 12);

    unsigned long long w = *reinterpret_cast<const unsigned long long*>(
        bytes + (size_t)row * 512 + (lane << 3));

    // Hoist wave-uniform epilogue inputs above the gather chain.
    float2 p = pIn[row];
    float2 st = make_float2(0.f, 0.f), k1v = make_float2(0.f, 0.f);
    float rr = 0.f;
    if (PHASE == 1) { st = gsrc[row]; k1v = k1buf[row]; rr = rbuf[row]; }

    const int colbase = lane << 6;
    float sx = 0.f, sy = 0.f;
    while (w) {
        int j = __builtin_ctzll(w);
        w &= (w - 1);
        float2 v = gb[colbase + j];
        sx += v.x; sy += v.y;
    }
#pragma unroll
    for (int m = 32; m >= 1; m >>= 1) {
        sx += __shfl_xor(sx, m, 64);
        sy += __shfl_xor(sy, m, 64);
    }

    if (lane == 0) {
        if (PHASE == 0) {
            float r   = sqrtf(p.x * p.x + p.y * p.y);
            float k1x = sx - p.x, k1y = sy - p.y;
            float tx  = p.x + DTS * k1x, ty = p.y + DTS * k1y;
            float sc  = r / (sqrtf(tx * tx + ty * ty) + EPS);
            k1buf[row]   = make_float2(k1x, k1y);
            starbuf[row] = make_float2(tx * sc, ty * sc);
            rbuf[row]    = r;
        } else {
            float k2x = sx - st.x, k2y = sy - st.y;
            float nx  = p.x + HALF_DT * (k1v.x + k2x);
            float ny  = p.y + HALF_DT * (k1v.y + k2y);
            float sc  = rr / (sqrtf(nx * nx + ny * ny) + EPS);
            outbuf[row] = make_float2(nx * sc, ny * sc);
        }
    }
}

extern "C" void kernel_launch(void* const* d_in, const int* in_sizes, int n_in,
                              void* d_out, int out_size, void* d_ws, size_t ws_size,
                              hipStream_t stream) {
    const float* psi  = (const float*)d_in[0];   // [4,4096,2] fp32
    const float* mask = (const float*)d_in[1];   // [4,4096,4096] fp32 (0/1)
    float2* out2 = (float2*)d_out;               // [4,4096,2] fp32

    // Workspace: byte-mask 8 MB | p 128 KB | k1 128 KB | star 128 KB | r 64 KB
    char* ws = (char*)d_ws;
    unsigned char* bytes = (unsigned char*)ws;
    float2* p    = (float2*)(ws + (size_t)TOT_BYTES);
    float2* k1   = p + NROWS;
    float2* star = k1 + NROWS;
    float*  rbuf = (float*)(star + NROWS);

    const float2* psi2 = (const float2*)psi;
    const int fgrid = NROWS / 4;                 // 4 waves (rows) per 256-thr block

    compress_bytes<<<CB_BLOCKS, CB_THR, 0, stream>>>(mask, bytes);

    // step 1 (reads psi from d_in, writes p into ws)
    force_step<0><<<fgrid, 256, 0, stream>>>(bytes, psi2, psi2, k1, star, rbuf, nullptr);
    force_step<1><<<fgrid, 256, 0, stream>>>(bytes, psi2, star, k1, star, rbuf, p);
    // step 2 (in-place p update; PHASE 1 only reads its own p[row])
    force_step<0><<<fgrid, 256, 0, stream>>>(bytes, p, p, k1, star, rbuf, nullptr);
    force_step<1><<<fgrid, 256, 0, stream>>>(bytes, p, star, k1, star, rbuf, p);
    // step 3 (writes final state straight to d_out)
    force_step<0><<<fgrid, 256, 0, stream>>>(bytes, p, p, k1, star, rbuf, nullptr);
    force_step<1><<<fgrid, 256, 0, stream>>>(bytes, p, star, k1, star, rbuf, out2);
}